// Round 1
// baseline (790.669 us; speedup 1.0000x reference)
//
#include <hip/hip_runtime.h>

#define NN 100000
#define EE 1600000
#define HF 128
#define GG 256
#define CCLS 10

// ---------------- utility ----------------
__global__ __launch_bounds__(256) void k_zero(float* __restrict__ p, int n) {
  int i = blockIdx.x * 256 + threadIdx.x;
  if (i < n) p[i] = 0.f;
}

// ---------------- CSR build ----------------
__global__ __launch_bounds__(256) void k_count(const int* __restrict__ ei, int* __restrict__ cnt) {
  int e = blockIdx.x * 256 + threadIdx.x;
  if (e < EE) atomicAdd(&cnt[ei[EE + e]], 1);
}

__global__ __launch_bounds__(256) void k_dis(const int* __restrict__ cnt, const float* __restrict__ nc,
                                             float* __restrict__ dis, float* __restrict__ cself) {
  int i = blockIdx.x * 256 + threadIdx.x;
  if (i < NN) {
    float d = (float)(cnt[i] + 1);           // +1 self loop
    dis[i] = rsqrtf(d);
    cself[i] = nc[i] / d;                    // dis^2 * node_centrality
  }
}

__global__ __launch_bounds__(256) void k_scan1(const int* __restrict__ cnt, int* __restrict__ rowptr,
                                               int* __restrict__ bsum) {
  int tid = threadIdx.x;
  int i = blockIdx.x * 256 + tid;
  int val = (i < NN) ? cnt[i] : 0;
  int lane = tid & 63, w = tid >> 6;
  int v = val;
  #pragma unroll
  for (int off = 1; off < 64; off <<= 1) {
    int t = __shfl_up(v, off, 64);
    if (lane >= off) v += t;
  }
  __shared__ int wsum[4];
  if (lane == 63) wsum[w] = v;
  __syncthreads();
  int woff = 0;
  for (int j = 0; j < w; ++j) woff += wsum[j];
  if (i < NN) rowptr[i] = woff + v - val;     // block-local exclusive
  if (tid == 255) bsum[blockIdx.x] = woff + v; // block total
}

__global__ __launch_bounds__(512) void k_scan2(const int* __restrict__ bsum, int* __restrict__ bofs,
                                               int* __restrict__ rowptr, int nb) {
  __shared__ int s[512];
  int tid = threadIdx.x;
  int orig = (tid < nb) ? bsum[tid] : 0;
  s[tid] = orig;
  __syncthreads();
  for (int off = 1; off < 512; off <<= 1) {
    int t = (tid >= off) ? s[tid - off] : 0;
    __syncthreads();
    s[tid] += t;
    __syncthreads();
  }
  if (tid < nb) bofs[tid] = s[tid] - orig;    // exclusive block offset
  if (tid == 511) rowptr[NN] = s[511];        // total == EE
}

__global__ __launch_bounds__(256) void k_scan3(int* __restrict__ rowptr, const int* __restrict__ bofs) {
  int i = blockIdx.x * 256 + threadIdx.x;
  if (i < NN) rowptr[i] += bofs[blockIdx.x];
}

__global__ __launch_bounds__(256) void k_fill(const int* __restrict__ ei, const float* __restrict__ ec,
                                              const float* __restrict__ dis, const int* __restrict__ rowptr,
                                              int* __restrict__ fillcnt, int* __restrict__ csr_row,
                                              float* __restrict__ csr_c) {
  int e = blockIdx.x * 256 + threadIdx.x;
  if (e >= EE) return;
  int r = ei[e];          // source (gather from)
  int c = ei[EE + e];     // target (aggregate to)
  int pos = rowptr[c] + atomicAdd(&fillcnt[c], 1);
  csr_row[pos] = r;
  csr_c[pos] = dis[r] * dis[c] * ec[e];
}

// ---------------- GEMM: H = act(X) @ W  (X:[NN,128], W:[128,128]) ----------------
__global__ __launch_bounds__(256) void k_gemm(const float* __restrict__ X, const float* __restrict__ W,
                                              float* __restrict__ H, int relu_in) {
  __shared__ float Xs[32 * 132];
  const int tid = threadIdx.x;
  const int rb = blockIdx.x * 32;
  // stage 32x128 X tile, optional relu
  #pragma unroll
  for (int t = 0; t < 16; ++t) {
    int idx = t * 256 + tid;
    int r = idx >> 7, k = idx & 127;
    float v = X[(size_t)(rb + r) * 128 + k];
    if (relu_in) v = fmaxf(v, 0.f);
    Xs[r * 132 + k] = v;
  }
  __syncthreads();
  const int c0 = (tid & 31) * 4;
  const int r0 = tid >> 5;                 // rows r0 + 8*i
  float acc[4][4] = {{0.f}};
  #pragma unroll 4
  for (int k = 0; k < 128; k += 2) {
    float4 w0 = *(const float4*)&W[k * 128 + c0];
    float4 w1 = *(const float4*)&W[(k + 1) * 128 + c0];
    #pragma unroll
    for (int i = 0; i < 4; ++i) {
      float2 xv = *(const float2*)&Xs[(r0 + 8 * i) * 132 + k];
      acc[i][0] += xv.x * w0.x; acc[i][1] += xv.x * w0.y;
      acc[i][2] += xv.x * w0.z; acc[i][3] += xv.x * w0.w;
      acc[i][0] += xv.y * w1.x; acc[i][1] += xv.y * w1.y;
      acc[i][2] += xv.y * w1.z; acc[i][3] += xv.y * w1.w;
    }
  }
  #pragma unroll
  for (int i = 0; i < 4; ++i) {
    float4 o = make_float4(acc[i][0], acc[i][1], acc[i][2], acc[i][3]);
    *(float4*)&H[(size_t)(rb + r0 + 8 * i) * 128 + c0] = o;
  }
}

// ---------------- aggregation: AGG[i] = b + cself[i]*H[i] + sum_e c_e * H[src_e] ----------------
__global__ __launch_bounds__(256) void k_aggregate(const float* __restrict__ H,
                                                   const int* __restrict__ csr_row,
                                                   const float* __restrict__ csr_c,
                                                   const int* __restrict__ rowptr,
                                                   const float* __restrict__ cself,
                                                   const float* __restrict__ bias,
                                                   float* __restrict__ AGG) {
  int wave = threadIdx.x >> 6, lane = threadIdx.x & 63;
  int i = blockIdx.x * 4 + wave;
  if (i >= NN) return;
  float acc0 = bias[lane], acc1 = bias[lane + 64];
  float cs = cself[i];
  const float* hp = H + (size_t)i * 128;
  acc0 += cs * hp[lane];
  acc1 += cs * hp[lane + 64];
  int k = rowptr[i], ke = rowptr[i + 1];
  for (; k + 1 < ke; k += 2) {
    int r0 = csr_row[k], r1 = csr_row[k + 1];
    float c0 = csr_c[k], c1 = csr_c[k + 1];
    const float* h0 = H + (size_t)r0 * 128;
    const float* h1 = H + (size_t)r1 * 128;
    float a = h0[lane], b = h0[lane + 64];
    float c = h1[lane], d = h1[lane + 64];
    acc0 += c0 * a; acc1 += c0 * b;
    acc0 += c1 * c; acc1 += c1 * d;
  }
  if (k < ke) {
    int r = csr_row[k]; float cc = csr_c[k];
    const float* h0 = H + (size_t)r * 128;
    acc0 += cc * h0[lane]; acc1 += cc * h0[lane + 64];
  }
  AGG[(size_t)i * 128 + lane] = acc0;
  AGG[(size_t)i * 128 + 64 + lane] = acc1;
}

// ---------------- pooling: pool[g] += relu(x[n]), cnt[g] += 1 ----------------
__global__ __launch_bounds__(128) void k_pool(const float* __restrict__ Xf, const int* __restrict__ batch,
                                              float* __restrict__ pool, float* __restrict__ cntg) {
  __shared__ int bsh[256];
  int f = threadIdx.x;
  int n0 = blockIdx.x * 256;
  int n1 = min(n0 + 256, NN);
  int cnt_here = n1 - n0;
  if (f < cnt_here) bsh[f] = batch[n0 + f];
  if (f + 128 < cnt_here) bsh[f + 128] = batch[n0 + f + 128];
  __syncthreads();
  int g = bsh[0];
  float acc = 0.f;
  int run = 0;
  for (int n = 0; n < cnt_here; ++n) {
    int gn = bsh[n];
    if (gn != g) {
      atomicAdd(&pool[(size_t)g * 128 + f], acc);
      if (f == 0) atomicAdd(&cntg[g], (float)run);
      acc = 0.f; run = 0; g = gn;
    }
    acc += fmaxf(Xf[(size_t)(n0 + n) * 128 + f], 0.f);
    run++;
  }
  atomicAdd(&pool[(size_t)g * 128 + f], acc);
  if (f == 0) atomicAdd(&cntg[g], (float)run);
}

// ---------------- head: out[g] = (pool[g]/max(cnt,1)) @ Wc + bc ----------------
__global__ __launch_bounds__(64) void k_head(const float* __restrict__ pool, const float* __restrict__ cntg,
                                             const float* __restrict__ Wc, const float* __restrict__ bc,
                                             float* __restrict__ out) {
  int g = blockIdx.x;
  int lane = threadIdx.x;
  float inv = 1.f / fmaxf(cntg[g], 1.f);
  float p0 = pool[(size_t)g * 128 + lane] * inv;
  float p1 = pool[(size_t)g * 128 + 64 + lane] * inv;
  #pragma unroll
  for (int c = 0; c < CCLS; ++c) {
    float s = p0 * Wc[lane * CCLS + c] + p1 * Wc[(lane + 64) * CCLS + c];
    s += __shfl_down(s, 32, 64);
    s += __shfl_down(s, 16, 64);
    s += __shfl_down(s, 8, 64);
    s += __shfl_down(s, 4, 64);
    s += __shfl_down(s, 2, 64);
    s += __shfl_down(s, 1, 64);
    if (lane == 0) out[g * CCLS + c] = s + bc[c];
  }
}

extern "C" void kernel_launch(void* const* d_in, const int* in_sizes, int n_in,
                              void* d_out, int out_size, void* d_ws, size_t ws_size,
                              hipStream_t stream) {
  const float* x  = (const float*)d_in[0];
  const int* ei   = (const int*)d_in[1];
  const int* batch = (const int*)d_in[2];
  const float* nc = (const float*)d_in[3];
  const float* ec = (const float*)d_in[4];
  const float* W1 = (const float*)d_in[5];
  const float* b1 = (const float*)d_in[6];
  const float* W2 = (const float*)d_in[7];
  const float* b2 = (const float*)d_in[8];
  const float* W3 = (const float*)d_in[9];
  const float* b3 = (const float*)d_in[10];
  const float* Wc = (const float*)d_in[11];
  const float* bc = (const float*)d_in[12];
  float* out = (float*)d_out;

  char* ws = (char*)d_ws;
  const size_t B1 = (size_t)NN * 128 * 4;        // 51.2 MB
  float* buf0    = (float*)(ws);                  // h
  float* buf1    = (float*)(ws + B1);             // x / agg
  int*   csr_row = (int*)(ws + 2 * B1);
  float* csr_c   = (float*)(ws + 2 * B1 + (size_t)EE * 4);
  char* p = ws + 2 * B1 + (size_t)EE * 8;
  int*   deg_cnt = (int*)(p);                 p += (size_t)NN * 4;
  int*   fillcnt = (int*)(p);                 p += (size_t)NN * 4;
  float* dis     = (float*)(p);               p += (size_t)NN * 4;
  float* cself   = (float*)(p);               p += (size_t)NN * 4;
  int*   rowptr  = (int*)(p);                 p += ((size_t)NN + 32) * 4;
  int*   bsum    = (int*)(p);                 p += 2048;
  int*   bofs    = (int*)(p);                 p += 2048;
  float* pool    = (float*)(p);               p += (size_t)GG * 128 * 4;
  float* cntg    = (float*)(p);               p += (size_t)GG * 4;

  const int ZN1 = 2 * NN;                 // deg_cnt + fillcnt (contiguous)
  const int ZN2 = GG * 128 + GG;          // pool + cntg (contiguous)
  const int nb_scan = (NN + 255) / 256;   // 391

  // CSR build
  k_zero<<<(ZN1 + 255) / 256, 256, 0, stream>>>((float*)deg_cnt, ZN1);
  k_zero<<<(ZN2 + 255) / 256, 256, 0, stream>>>(pool, ZN2);
  k_count<<<(EE + 255) / 256, 256, 0, stream>>>(ei, deg_cnt);
  k_dis<<<(NN + 255) / 256, 256, 0, stream>>>(deg_cnt, nc, dis, cself);
  k_scan1<<<nb_scan, 256, 0, stream>>>(deg_cnt, rowptr, bsum);
  k_scan2<<<1, 512, 0, stream>>>(bsum, bofs, rowptr, nb_scan);
  k_scan3<<<nb_scan, 256, 0, stream>>>(rowptr, bofs);
  k_fill<<<(EE + 255) / 256, 256, 0, stream>>>(ei, ec, dis, rowptr, fillcnt, csr_row, csr_c);

  // 3 GCN layers: gemm -> aggregate (ping-pong buf1 <-> buf0)
  const float* Ws[3] = {W1, W2, W3};
  const float* bs[3] = {b1, b2, b3};
  const float* xin = x;
  for (int l = 0; l < 3; ++l) {
    k_gemm<<<NN / 32, 256, 0, stream>>>(xin, Ws[l], buf0, l > 0 ? 1 : 0);
    k_aggregate<<<NN / 4, 256, 0, stream>>>(buf0, csr_row, csr_c, rowptr, cself, bs[l], buf1);
    xin = buf1;
  }

  // pooling + head
  k_pool<<<(NN + 255) / 256, 128, 0, stream>>>(buf1, batch, pool, cntg);
  k_head<<<GG, 64, 0, stream>>>(pool, cntg, Wc, bc, out);
}

// Round 4
// 579.288 us; speedup vs baseline: 1.3649x; 1.3649x over previous
//
#include <hip/hip_runtime.h>
#include <hip/hip_bf16.h>

#define NN 100000
#define EE 1600000
#define HF 128
#define GG 256
#define CCLS 10

typedef __attribute__((ext_vector_type(8))) short bf16x8;
typedef __attribute__((ext_vector_type(4))) float f32x4;

#define WT_PITCH 136   // shorts; 272 B row pitch -> 16B-aligned b128 reads, 2-way banks (free)

// ---------------- utility ----------------
__global__ __launch_bounds__(256) void k_zero(float* __restrict__ p, int n) {
  int i = blockIdx.x * 256 + threadIdx.x;
  if (i < n) p[i] = 0.f;
}

// ---------------- CSR build ----------------
__global__ __launch_bounds__(256) void k_count(const int* __restrict__ ei, int* __restrict__ cnt) {
  int e = blockIdx.x * 256 + threadIdx.x;
  if (e < EE) atomicAdd(&cnt[ei[EE + e]], 1);
}

__global__ __launch_bounds__(256) void k_dis(const int* __restrict__ cnt, const float* __restrict__ nc,
                                             float* __restrict__ dis, float* __restrict__ cself) {
  int i = blockIdx.x * 256 + threadIdx.x;
  if (i < NN) {
    float d = (float)(cnt[i] + 1);           // +1 self loop
    dis[i] = rsqrtf(d);
    cself[i] = nc[i] / d;                    // dis^2 * node_centrality
  }
}

__global__ __launch_bounds__(256) void k_scan1(const int* __restrict__ cnt, int* __restrict__ rowptr,
                                               int* __restrict__ bsum) {
  int tid = threadIdx.x;
  int i = blockIdx.x * 256 + tid;
  int val = (i < NN) ? cnt[i] : 0;
  int lane = tid & 63, w = tid >> 6;
  int v = val;
  #pragma unroll
  for (int off = 1; off < 64; off <<= 1) {
    int t = __shfl_up(v, off, 64);
    if (lane >= off) v += t;
  }
  __shared__ int wsum[4];
  if (lane == 63) wsum[w] = v;
  __syncthreads();
  int woff = 0;
  for (int j = 0; j < w; ++j) woff += wsum[j];
  if (i < NN) rowptr[i] = woff + v - val;     // block-local exclusive
  if (tid == 255) bsum[blockIdx.x] = woff + v; // block total
}

__global__ __launch_bounds__(512) void k_scan2(const int* __restrict__ bsum, int* __restrict__ bofs,
                                               int* __restrict__ rowptr, int nb) {
  __shared__ int s[512];
  int tid = threadIdx.x;
  int orig = (tid < nb) ? bsum[tid] : 0;
  s[tid] = orig;
  __syncthreads();
  for (int off = 1; off < 512; off <<= 1) {
    int t = (tid >= off) ? s[tid - off] : 0;
    __syncthreads();
    s[tid] += t;
    __syncthreads();
  }
  if (tid < nb) bofs[tid] = s[tid] - orig;    // exclusive block offset
  if (tid == 511) rowptr[NN] = s[511];        // total == EE
}

__global__ __launch_bounds__(256) void k_scan3(int* __restrict__ rowptr, const int* __restrict__ bofs) {
  int i = blockIdx.x * 256 + threadIdx.x;
  if (i < NN) rowptr[i] += bofs[blockIdx.x];
}

__global__ __launch_bounds__(256) void k_fill(const int* __restrict__ ei, const float* __restrict__ ec,
                                              const float* __restrict__ dis, const int* __restrict__ rowptr,
                                              int* __restrict__ fillcnt, int2* __restrict__ csr) {
  int e = blockIdx.x * 256 + threadIdx.x;
  if (e >= EE) return;
  int r = ei[e];          // source (gather from)
  int c = ei[EE + e];     // target (aggregate to)
  int pos = rowptr[c] + atomicAdd(&fillcnt[c], 1);
  csr[pos] = make_int2(r, __float_as_int(dis[r] * dis[c] * ec[e]));
}

// ---------------- MFMA GEMM: H[bf16] = act(X) @ W  (X:[NN,128] f32, W:[128,128] f32) ----------------
__global__ __launch_bounds__(256) void k_gemm(const float* __restrict__ X, const float* __restrict__ W,
                                              __hip_bfloat16* __restrict__ H, int relu_in) {
  __shared__ short Wt[128 * WT_PITCH];   // Wt[c][k] bf16, 34.8 KB
  const int tid = threadIdx.x;
  // stage W transposed + converted: idx = c + 128*kp, covering k = 2kp, 2kp+1
  #pragma unroll
  for (int t = 0; t < 32; ++t) {
    int idx = t * 256 + tid;
    int c = idx & 127, kp = idx >> 7;      // kp 0..63
    float w0 = W[(2 * kp) * 128 + c];
    float w1 = W[(2 * kp + 1) * 128 + c];
    __hip_bfloat16 h0 = __float2bfloat16(w0);
    __hip_bfloat16 h1 = __float2bfloat16(w1);
    short2 s2;
    s2.x = *(short*)&h0; s2.y = *(short*)&h1;
    *(short2*)&Wt[c * WT_PITCH + 2 * kp] = s2;
  }
  __syncthreads();

  const int wv = tid >> 6, lane = tid & 63;
  const int r15 = lane & 15, kgrp = lane >> 4;   // A row-in-tile, k group
  const int arow = blockIdx.x * 64 + wv * 16 + r15;
  const float* xrow = X + (size_t)arow * 128;
  f32x4 acc[8] = {};

  #pragma unroll
  for (int kk = 0; kk < 4; ++kk) {
    const int kbase = kk * 32 + kgrp * 8;
    bf16x8 afrag;
    if (arow < NN) {
      float4 xa = *(const float4*)&xrow[kbase];
      float4 xb = *(const float4*)&xrow[kbase + 4];
      float xv[8] = {xa.x, xa.y, xa.z, xa.w, xb.x, xb.y, xb.z, xb.w};
      #pragma unroll
      for (int j = 0; j < 8; ++j) {
        float v = relu_in ? fmaxf(xv[j], 0.f) : xv[j];
        __hip_bfloat16 b = __float2bfloat16(v);
        afrag[j] = *(short*)&b;
      }
    } else {
      #pragma unroll
      for (int j = 0; j < 8; ++j) afrag[j] = 0;
    }
    #pragma unroll
    for (int cb = 0; cb < 8; ++cb) {
      bf16x8 bfrag = *(const bf16x8*)&Wt[(cb * 16 + r15) * WT_PITCH + kbase];
      acc[cb] = __builtin_amdgcn_mfma_f32_16x16x32_bf16(afrag, bfrag, acc[cb], 0, 0, 0);
    }
  }

  // D: col = lane&15, row = (lane>>4)*4 + reg
  const int orow0 = blockIdx.x * 64 + wv * 16 + kgrp * 4;
  #pragma unroll
  for (int r = 0; r < 4; ++r) {
    int orow = orow0 + r;
    if (orow < NN) {
      #pragma unroll
      for (int cb = 0; cb < 8; ++cb) {
        H[(size_t)orow * 128 + cb * 16 + r15] = __float2bfloat16(acc[cb][r]);
      }
    }
  }
}

// ---------------- aggregation: AGG[i] = b + cself[i]*H[i] + sum_e c_e * H[src_e]  (H bf16, AGG f32) ----------------
__global__ __launch_bounds__(256) void k_aggregate(const __hip_bfloat16* __restrict__ H,
                                                   const int2* __restrict__ csr,
                                                   const int* __restrict__ rowptr,
                                                   const float* __restrict__ cself,
                                                   const float* __restrict__ bias,
                                                   float* __restrict__ AGG) {
  int wave = threadIdx.x >> 6, lane = threadIdx.x & 63;
  int i = blockIdx.x * 4 + wave;
  if (i >= NN) return;
  float2 bb = *(const float2*)&bias[lane * 2];
  float acc0 = bb.x, acc1 = bb.y;     // cols 2*lane, 2*lane+1
  const uint* Hu = (const uint*)H;    // packed bf16x2 per uint
  float cs = cself[i];
  {
    uint u = Hu[(size_t)i * 64 + lane];
    acc0 += cs * __uint_as_float(u << 16);
    acc1 += cs * __uint_as_float(u & 0xffff0000u);
  }
  int k = rowptr[i], ke = rowptr[i + 1];
  for (; k + 1 < ke; k += 2) {
    int2 e0 = csr[k], e1 = csr[k + 1];
    float c0 = __int_as_float(e0.y), c1 = __int_as_float(e1.y);
    uint u0 = Hu[(size_t)e0.x * 64 + lane];
    uint u1 = Hu[(size_t)e1.x * 64 + lane];
    acc0 += c0 * __uint_as_float(u0 << 16);
    acc1 += c0 * __uint_as_float(u0 & 0xffff0000u);
    acc0 += c1 * __uint_as_float(u1 << 16);
    acc1 += c1 * __uint_as_float(u1 & 0xffff0000u);
  }
  if (k < ke) {
    int2 e0 = csr[k];
    float c0 = __int_as_float(e0.y);
    uint u0 = Hu[(size_t)e0.x * 64 + lane];
    acc0 += c0 * __uint_as_float(u0 << 16);
    acc1 += c0 * __uint_as_float(u0 & 0xffff0000u);
  }
  float2 o; o.x = acc0; o.y = acc1;
  *(float2*)&AGG[(size_t)i * 128 + lane * 2] = o;
}

// ---------------- pooling: pool[g] += relu(x[n]), cnt[g] += 1 ----------------
__global__ __launch_bounds__(128) void k_pool(const float* __restrict__ Xf, const int* __restrict__ batch,
                                              float* __restrict__ pool, float* __restrict__ cntg) {
  __shared__ int bsh[256];
  int f = threadIdx.x;
  int n0 = blockIdx.x * 256;
  int n1 = min(n0 + 256, NN);
  int cnt_here = n1 - n0;
  if (f < cnt_here) bsh[f] = batch[n0 + f];
  if (f + 128 < cnt_here) bsh[f + 128] = batch[n0 + f + 128];
  __syncthreads();
  int g = bsh[0];
  float acc = 0.f;
  int run = 0;
  for (int n = 0; n < cnt_here; ++n) {
    int gn = bsh[n];
    if (gn != g) {
      atomicAdd(&pool[(size_t)g * 128 + f], acc);
      if (f == 0) atomicAdd(&cntg[g], (float)run);
      acc = 0.f; run = 0; g = gn;
    }
    acc += fmaxf(Xf[(size_t)(n0 + n) * 128 + f], 0.f);
    run++;
  }
  atomicAdd(&pool[(size_t)g * 128 + f], acc);
  if (f == 0) atomicAdd(&cntg[g], (float)run);
}

// ---------------- head: out[g] = (pool[g]/max(cnt,1)) @ Wc + bc ----------------
__global__ __launch_bounds__(64) void k_head(const float* __restrict__ pool, const float* __restrict__ cntg,
                                             const float* __restrict__ Wc, const float* __restrict__ bc,
                                             float* __restrict__ out) {
  int g = blockIdx.x;
  int lane = threadIdx.x;
  float inv = 1.f / fmaxf(cntg[g], 1.f);
  float p0 = pool[(size_t)g * 128 + lane] * inv;
  float p1 = pool[(size_t)g * 128 + 64 + lane] * inv;
  #pragma unroll
  for (int c = 0; c < CCLS; ++c) {
    float s = p0 * Wc[lane * CCLS + c] + p1 * Wc[(lane + 64) * CCLS + c];
    s += __shfl_down(s, 32, 64);
    s += __shfl_down(s, 16, 64);
    s += __shfl_down(s, 8, 64);
    s += __shfl_down(s, 4, 64);
    s += __shfl_down(s, 2, 64);
    s += __shfl_down(s, 1, 64);
    if (lane == 0) out[g * CCLS + c] = s + bc[c];
  }
}

extern "C" void kernel_launch(void* const* d_in, const int* in_sizes, int n_in,
                              void* d_out, int out_size, void* d_ws, size_t ws_size,
                              hipStream_t stream) {
  const float* x  = (const float*)d_in[0];
  const int* ei   = (const int*)d_in[1];
  const int* batch = (const int*)d_in[2];
  const float* nc = (const float*)d_in[3];
  const float* ec = (const float*)d_in[4];
  const float* W1 = (const float*)d_in[5];
  const float* b1 = (const float*)d_in[6];
  const float* W2 = (const float*)d_in[7];
  const float* b2 = (const float*)d_in[8];
  const float* W3 = (const float*)d_in[9];
  const float* b3 = (const float*)d_in[10];
  const float* Wc = (const float*)d_in[11];
  const float* bc = (const float*)d_in[12];
  float* out = (float*)d_out;

  char* ws = (char*)d_ws;
  const size_t BAGG = (size_t)NN * 128 * 4;      // 51.2 MB fp32
  const size_t BH   = (size_t)NN * 128 * 2;      // 25.6 MB bf16
  float* agg             = (float*)(ws);
  __hip_bfloat16* hbuf   = (__hip_bfloat16*)(ws + BAGG);
  int2* csr              = (int2*)(ws + BAGG + BH);
  char* p = ws + BAGG + BH + (size_t)EE * 8;
  int*   deg_cnt = (int*)(p);                 p += (size_t)NN * 4;
  int*   fillcnt = (int*)(p);                 p += (size_t)NN * 4;
  float* dis     = (float*)(p);               p += (size_t)NN * 4;
  float* cself   = (float*)(p);               p += (size_t)NN * 4;
  int*   rowptr  = (int*)(p);                 p += ((size_t)NN + 32) * 4;
  int*   bsum    = (int*)(p);                 p += 2048;
  int*   bofs    = (int*)(p);                 p += 2048;
  float* pool    = (float*)(p);               p += (size_t)GG * 128 * 4;
  float* cntg    = (float*)(p);               p += (size_t)GG * 4;

  const int ZN1 = 2 * NN;                 // deg_cnt + fillcnt (contiguous)
  const int ZN2 = GG * 128 + GG;          // pool + cntg (contiguous)
  const int nb_scan = (NN + 255) / 256;   // 391

  // CSR build
  k_zero<<<(ZN1 + 255) / 256, 256, 0, stream>>>((float*)deg_cnt, ZN1);
  k_zero<<<(ZN2 + 255) / 256, 256, 0, stream>>>(pool, ZN2);
  k_count<<<(EE + 255) / 256, 256, 0, stream>>>(ei, deg_cnt);
  k_dis<<<(NN + 255) / 256, 256, 0, stream>>>(deg_cnt, nc, dis, cself);
  k_scan1<<<nb_scan, 256, 0, stream>>>(deg_cnt, rowptr, bsum);
  k_scan2<<<1, 512, 0, stream>>>(bsum, bofs, rowptr, nb_scan);
  k_scan3<<<nb_scan, 256, 0, stream>>>(rowptr, bofs);
  k_fill<<<(EE + 255) / 256, 256, 0, stream>>>(ei, ec, dis, rowptr, fillcnt, csr);

  // 3 GCN layers: mfma-gemm (f32 in -> bf16 out) -> aggregate (bf16 gather -> f32 out)
  const float* Ws[3] = {W1, W2, W3};
  const float* bs[3] = {b1, b2, b3};
  const float* xin = x;
  const int gemm_grid = (NN + 63) / 64;
  for (int l = 0; l < 3; ++l) {
    k_gemm<<<gemm_grid, 256, 0, stream>>>(xin, Ws[l], hbuf, l > 0 ? 1 : 0);
    k_aggregate<<<(NN + 3) / 4, 256, 0, stream>>>(hbuf, csr, rowptr, cself, bs[l], agg);
    xin = agg;
  }

  // pooling + head
  k_pool<<<(NN + 255) / 256, 128, 0, stream>>>(agg, batch, pool, cntg);
  k_head<<<GG, 64, 0, stream>>>(pool, cntg, Wc, bc, out);
}

// Round 5
// 459.764 us; speedup vs baseline: 1.7197x; 1.2600x over previous
//
#include <hip/hip_runtime.h>
#include <hip/hip_bf16.h>

#define NN 100000
#define EE 1600000
#define HF 128
#define GG 256
#define CCLS 10

typedef __attribute__((ext_vector_type(8))) short bf16x8;
typedef __attribute__((ext_vector_type(4))) float f32x4;

#define WT_PITCH 136   // shorts; 272 B row pitch -> 16B-aligned b128 reads, 2-way banks (free)

__device__ __forceinline__ float bflo(uint u) { return __uint_as_float(u << 16); }
__device__ __forceinline__ float bfhi(uint u) { return __uint_as_float(u & 0xffff0000u); }
__device__ __forceinline__ uint packbf(float a, float b) {
  __hip_bfloat16 x = __float2bfloat16(a), y = __float2bfloat16(b);
  return (uint)*(unsigned short*)&x | ((uint)*(unsigned short*)&y << 16);
}

// ---------------- utility ----------------
__global__ __launch_bounds__(256) void k_zero(float* __restrict__ p, int n) {
  int i = blockIdx.x * 256 + threadIdx.x;
  if (i < n) p[i] = 0.f;
}

// ---------------- CSR build ----------------
__global__ __launch_bounds__(256) void k_count(const int* __restrict__ ei, int* __restrict__ cnt) {
  int e = blockIdx.x * 256 + threadIdx.x;
  if (e < EE) atomicAdd(&cnt[ei[EE + e]], 1);
}

__global__ __launch_bounds__(256) void k_dis(const int* __restrict__ cnt, const float* __restrict__ nc,
                                             float* __restrict__ dis, float* __restrict__ cself) {
  int i = blockIdx.x * 256 + threadIdx.x;
  if (i < NN) {
    float d = (float)(cnt[i] + 1);           // +1 self loop
    dis[i] = rsqrtf(d);
    cself[i] = nc[i] / d;                    // dis^2 * node_centrality
  }
}

__global__ __launch_bounds__(256) void k_scan1(const int* __restrict__ cnt, int* __restrict__ rowptr,
                                               int* __restrict__ bsum) {
  int tid = threadIdx.x;
  int i = blockIdx.x * 256 + tid;
  int val = (i < NN) ? cnt[i] : 0;
  int lane = tid & 63, w = tid >> 6;
  int v = val;
  #pragma unroll
  for (int off = 1; off < 64; off <<= 1) {
    int t = __shfl_up(v, off, 64);
    if (lane >= off) v += t;
  }
  __shared__ int wsum[4];
  if (lane == 63) wsum[w] = v;
  __syncthreads();
  int woff = 0;
  for (int j = 0; j < w; ++j) woff += wsum[j];
  if (i < NN) rowptr[i] = woff + v - val;     // block-local exclusive
  if (tid == 255) bsum[blockIdx.x] = woff + v; // block total
}

__global__ __launch_bounds__(512) void k_scan2(const int* __restrict__ bsum, int* __restrict__ bofs,
                                               int* __restrict__ rowptr, int nb) {
  __shared__ int s[512];
  int tid = threadIdx.x;
  int orig = (tid < nb) ? bsum[tid] : 0;
  s[tid] = orig;
  __syncthreads();
  for (int off = 1; off < 512; off <<= 1) {
    int t = (tid >= off) ? s[tid - off] : 0;
    __syncthreads();
    s[tid] += t;
    __syncthreads();
  }
  if (tid < nb) bofs[tid] = s[tid] - orig;    // exclusive block offset
  if (tid == 511) rowptr[NN] = s[511];        // total == EE
}

__global__ __launch_bounds__(256) void k_scan3(int* __restrict__ rowptr, const int* __restrict__ bofs) {
  int i = blockIdx.x * 256 + threadIdx.x;
  if (i < NN) rowptr[i] += bofs[blockIdx.x];
}

__global__ __launch_bounds__(256) void k_fill(const int* __restrict__ ei, const float* __restrict__ ec,
                                              const float* __restrict__ dis, const int* __restrict__ rowptr,
                                              int* __restrict__ fillcnt, int2* __restrict__ csr) {
  int e = blockIdx.x * 256 + threadIdx.x;
  if (e >= EE) return;
  int r = ei[e];          // source (gather from)
  int c = ei[EE + e];     // target (aggregate to)
  int pos = rowptr[c] + atomicAdd(&fillcnt[c], 1);
  csr[pos] = make_int2(r, __float_as_int(dis[r] * dis[c] * ec[e]));
}

// ---------------- MFMA GEMM: H[bf16] = X @ W  (X f32 [layer0] or relu'd bf16, W:[128,128] f32) ----------------
template<int INF32>
__global__ __launch_bounds__(256) void k_gemm(const void* __restrict__ Xv, const float* __restrict__ W,
                                              __hip_bfloat16* __restrict__ H) {
  __shared__ short Wt[128 * WT_PITCH];   // Wt[c][k] bf16, 34.8 KB
  const int tid = threadIdx.x;
  #pragma unroll
  for (int t = 0; t < 32; ++t) {
    int idx = t * 256 + tid;
    int c = idx & 127, kp = idx >> 7;      // kp 0..63
    float w0 = W[(2 * kp) * 128 + c];
    float w1 = W[(2 * kp + 1) * 128 + c];
    *(uint*)&Wt[c * WT_PITCH + 2 * kp] = packbf(w0, w1);
  }
  __syncthreads();

  const int wv = tid >> 6, lane = tid & 63;
  const int r15 = lane & 15, kgrp = lane >> 4;   // A row-in-tile, k group
  const int arow = blockIdx.x * 64 + wv * 16 + r15;
  f32x4 acc[8] = {};

  #pragma unroll
  for (int kk = 0; kk < 4; ++kk) {
    const int kbase = kk * 32 + kgrp * 8;
    bf16x8 afrag;
    if (arow < NN) {
      if constexpr (INF32) {
        const float* xrow = (const float*)Xv + (size_t)arow * 128;
        float4 xa = *(const float4*)&xrow[kbase];
        float4 xb = *(const float4*)&xrow[kbase + 4];
        uint p0 = packbf(xa.x, xa.y), p1 = packbf(xa.z, xa.w);
        uint p2 = packbf(xb.x, xb.y), p3 = packbf(xb.z, xb.w);
        afrag[0] = (short)(p0 & 0xffff); afrag[1] = (short)(p0 >> 16);
        afrag[2] = (short)(p1 & 0xffff); afrag[3] = (short)(p1 >> 16);
        afrag[4] = (short)(p2 & 0xffff); afrag[5] = (short)(p2 >> 16);
        afrag[6] = (short)(p3 & 0xffff); afrag[7] = (short)(p3 >> 16);
      } else {
        const short* xrow = (const short*)Xv + (size_t)arow * 128;
        afrag = *(const bf16x8*)&xrow[kbase];
      }
    } else {
      #pragma unroll
      for (int j = 0; j < 8; ++j) afrag[j] = 0;
    }
    #pragma unroll
    for (int cb = 0; cb < 8; ++cb) {
      bf16x8 bfrag = *(const bf16x8*)&Wt[(cb * 16 + r15) * WT_PITCH + kbase];
      acc[cb] = __builtin_amdgcn_mfma_f32_16x16x32_bf16(afrag, bfrag, acc[cb], 0, 0, 0);
    }
  }

  // D: col = lane&15, row = (lane>>4)*4 + reg
  const int orow0 = blockIdx.x * 64 + wv * 16 + kgrp * 4;
  #pragma unroll
  for (int r = 0; r < 4; ++r) {
    int orow = orow0 + r;
    if (orow < NN) {
      #pragma unroll
      for (int cb = 0; cb < 8; ++cb) {
        H[(size_t)orow * 128 + cb * 16 + r15] = __float2bfloat16(acc[cb][r]);
      }
    }
  }
}

// ---------------- aggregation: AGGB[i] = relu(b + cself[i]*H[i] + sum_e c_e*H[src_e])  (bf16 in/out) ----------------
__global__ __launch_bounds__(64) void k_aggregate(const __hip_bfloat16* __restrict__ H,
                                                  const int2* __restrict__ csr,
                                                  const int* __restrict__ rowptr,
                                                  const float* __restrict__ cself,
                                                  const float* __restrict__ bias,
                                                  uint* __restrict__ AGGB) {
  const int lane = threadIdx.x;
  const int i = blockIdx.x;
  float2 bb = *(const float2*)&bias[lane * 2];
  float acc0 = bb.x, acc1 = bb.y;     // features 2*lane, 2*lane+1
  const uint* Hu = (const uint*)H;    // packed bf16x2 per uint
  float cs = cself[i];
  {
    uint u = Hu[(size_t)i * 64 + lane];
    acc0 += cs * bflo(u);
    acc1 += cs * bfhi(u);
  }
  int k = rowptr[i], ke = rowptr[i + 1];
  for (; k + 3 < ke; k += 4) {
    int2 e0 = csr[k], e1 = csr[k + 1], e2 = csr[k + 2], e3 = csr[k + 3];
    uint u0 = Hu[(size_t)e0.x * 64 + lane];
    uint u1 = Hu[(size_t)e1.x * 64 + lane];
    uint u2 = Hu[(size_t)e2.x * 64 + lane];
    uint u3 = Hu[(size_t)e3.x * 64 + lane];
    float c0 = __int_as_float(e0.y), c1 = __int_as_float(e1.y);
    float c2 = __int_as_float(e2.y), c3 = __int_as_float(e3.y);
    acc0 += c0 * bflo(u0); acc1 += c0 * bfhi(u0);
    acc0 += c1 * bflo(u1); acc1 += c1 * bfhi(u1);
    acc0 += c2 * bflo(u2); acc1 += c2 * bfhi(u2);
    acc0 += c3 * bflo(u3); acc1 += c3 * bfhi(u3);
  }
  for (; k < ke; ++k) {
    int2 e0 = csr[k];
    float c0 = __int_as_float(e0.y);
    uint u0 = Hu[(size_t)e0.x * 64 + lane];
    acc0 += c0 * bflo(u0); acc1 += c0 * bfhi(u0);
  }
  AGGB[(size_t)i * 64 + lane] = packbf(fmaxf(acc0, 0.f), fmaxf(acc1, 0.f));
}

// ---------------- pooling: pool[g] += aggb[n] (already relu'd), cnt[g] += 1 ----------------
__global__ __launch_bounds__(64) void k_pool(const uint* __restrict__ Hb, const int* __restrict__ batch,
                                             float* __restrict__ pool, float* __restrict__ cntg) {
  __shared__ int bsh[256];
  int f = threadIdx.x;   // 0..63, features 2f, 2f+1
  int n0 = blockIdx.x * 256;
  int nh = min(256, NN - n0);
  for (int t = f; t < nh; t += 64) bsh[t] = batch[n0 + t];
  __syncthreads();
  int g = bsh[0];
  float a0 = 0.f, a1 = 0.f;
  int run = 0;
  for (int n = 0; n < nh; ++n) {
    int gn = bsh[n];
    if (gn != g) {
      atomicAdd(&pool[(size_t)g * 128 + 2 * f], a0);
      atomicAdd(&pool[(size_t)g * 128 + 2 * f + 1], a1);
      if (f == 0) atomicAdd(&cntg[g], (float)run);
      a0 = a1 = 0.f; run = 0; g = gn;
    }
    uint u = Hb[(size_t)(n0 + n) * 64 + f];
    a0 += bflo(u); a1 += bfhi(u);
    run++;
  }
  atomicAdd(&pool[(size_t)g * 128 + 2 * f], a0);
  atomicAdd(&pool[(size_t)g * 128 + 2 * f + 1], a1);
  if (f == 0) atomicAdd(&cntg[g], (float)run);
}

// ---------------- head: out[g] = (pool[g]/max(cnt,1)) @ Wc + bc ----------------
__global__ __launch_bounds__(64) void k_head(const float* __restrict__ pool, const float* __restrict__ cntg,
                                             const float* __restrict__ Wc, const float* __restrict__ bc,
                                             float* __restrict__ out) {
  int g = blockIdx.x;
  int lane = threadIdx.x;
  float inv = 1.f / fmaxf(cntg[g], 1.f);
  float p0 = pool[(size_t)g * 128 + lane] * inv;
  float p1 = pool[(size_t)g * 128 + 64 + lane] * inv;
  #pragma unroll
  for (int c = 0; c < CCLS; ++c) {
    float s = p0 * Wc[lane * CCLS + c] + p1 * Wc[(lane + 64) * CCLS + c];
    s += __shfl_down(s, 32, 64);
    s += __shfl_down(s, 16, 64);
    s += __shfl_down(s, 8, 64);
    s += __shfl_down(s, 4, 64);
    s += __shfl_down(s, 2, 64);
    s += __shfl_down(s, 1, 64);
    if (lane == 0) out[g * CCLS + c] = s + bc[c];
  }
}

extern "C" void kernel_launch(void* const* d_in, const int* in_sizes, int n_in,
                              void* d_out, int out_size, void* d_ws, size_t ws_size,
                              hipStream_t stream) {
  const float* x  = (const float*)d_in[0];
  const int* ei   = (const int*)d_in[1];
  const int* batch = (const int*)d_in[2];
  const float* nc = (const float*)d_in[3];
  const float* ec = (const float*)d_in[4];
  const float* W1 = (const float*)d_in[5];
  const float* b1 = (const float*)d_in[6];
  const float* W2 = (const float*)d_in[7];
  const float* b2 = (const float*)d_in[8];
  const float* W3 = (const float*)d_in[9];
  const float* b3 = (const float*)d_in[10];
  const float* Wc = (const float*)d_in[11];
  const float* bc = (const float*)d_in[12];
  float* out = (float*)d_out;

  char* ws = (char*)d_ws;
  const size_t BH = (size_t)NN * 128 * 2;        // 25.6 MB bf16
  __hip_bfloat16* hbuf = (__hip_bfloat16*)(ws);
  uint* aggb           = (uint*)(ws + BH);
  int2* csr            = (int2*)(ws + 2 * BH);
  char* p = ws + 2 * BH + (size_t)EE * 8;
  int*   deg_cnt = (int*)(p);                 p += (size_t)NN * 4;
  int*   fillcnt = (int*)(p);                 p += (size_t)NN * 4;
  float* dis     = (float*)(p);               p += (size_t)NN * 4;
  float* cself   = (float*)(p);               p += (size_t)NN * 4;
  int*   rowptr  = (int*)(p);                 p += ((size_t)NN + 32) * 4;
  int*   bsum    = (int*)(p);                 p += 2048;
  int*   bofs    = (int*)(p);                 p += 2048;
  float* pool    = (float*)(p);               p += (size_t)GG * 128 * 4;
  float* cntg    = (float*)(p);               p += (size_t)GG * 4;

  const int ZN1 = 2 * NN;                 // deg_cnt + fillcnt (contiguous)
  const int ZN2 = GG * 128 + GG;          // pool + cntg (contiguous)
  const int nb_scan = (NN + 255) / 256;   // 391

  // CSR build
  k_zero<<<(ZN1 + 255) / 256, 256, 0, stream>>>((float*)deg_cnt, ZN1);
  k_zero<<<(ZN2 + 255) / 256, 256, 0, stream>>>(pool, ZN2);
  k_count<<<(EE + 255) / 256, 256, 0, stream>>>(ei, deg_cnt);
  k_dis<<<(NN + 255) / 256, 256, 0, stream>>>(deg_cnt, nc, dis, cself);
  k_scan1<<<nb_scan, 256, 0, stream>>>(deg_cnt, rowptr, bsum);
  k_scan2<<<1, 512, 0, stream>>>(bsum, bofs, rowptr, nb_scan);
  k_scan3<<<nb_scan, 256, 0, stream>>>(rowptr, bofs);
  k_fill<<<(EE + 255) / 256, 256, 0, stream>>>(ei, ec, dis, rowptr, fillcnt, csr);

  // 3 GCN layers: mfma-gemm -> aggregate (relu'd bf16 out)
  const float* Ws[3] = {W1, W2, W3};
  const float* bs[3] = {b1, b2, b3};
  const int gemm_grid = (NN + 63) / 64;
  for (int l = 0; l < 3; ++l) {
    if (l == 0) k_gemm<1><<<gemm_grid, 256, 0, stream>>>((const void*)x, Ws[l], hbuf);
    else        k_gemm<0><<<gemm_grid, 256, 0, stream>>>((const void*)aggb, Ws[l], hbuf);
    k_aggregate<<<NN, 64, 0, stream>>>(hbuf, csr, rowptr, cself, bs[l], aggb);
  }

  // pooling + head
  k_pool<<<(NN + 255) / 256, 64, 0, stream>>>(aggb, batch, pool, cntg);
  k_head<<<GG, 64, 0, stream>>>(pool, cntg, Wc, bc, out);
}